// Round 1
// baseline (120.084 us; speedup 1.0000x reference)
//
#include <hip/hip_runtime.h>

// Local 5x5 window dot-product attention (fp32).
//   attn[p,k] = dot_c(main[p,c], ref[p+off_k, c])      (0 if OOB, zero-padded)
//   w = softmax_k(attn)
//   out[p,i]  = sum_k w[k] * ref_value[p+off_k, i]     (0 if OOB)
// B=2, H=W=256, C=BIN=32, K=5 (25 offsets).
//
// Wave layout: 64 lanes = 16 consecutive pixels (same row) x 4 channel-groups
// (8 channels each). All global accesses are contiguous 2KB per wave-instruction.
// Score reduction across the 4 channel-group lanes via quad-local shfl_xor (DPP).

#define HW_PIX 65536   // H*W

__global__ void local_attn_kernel(const float* __restrict__ main_p,
                                  const float* __restrict__ ref_p,
                                  const float* __restrict__ rv_p,
                                  float* __restrict__ out_p)
{
    const int lane = threadIdx.x & 63;
    const int wv   = threadIdx.x >> 6;
    const int cg   = lane & 3;          // channel group: channels cg*8 .. cg*8+7
    const int pw   = lane >> 2;         // pixel within wave: 0..15
    const int p    = blockIdx.x * 64 + wv * 16 + pw;   // global pixel index

    const int rem = p & (HW_PIX - 1);   // index within one batch image
    const int h   = rem >> 8;
    const int w   = rem & 255;

    const float4* m4 = (const float4*)main_p;
    const float4* r4 = (const float4*)ref_p;
    const float4* v4 = (const float4*)rv_p;
    float4*       o4 = (float4*)out_p;

    const int vbase = p * 8 + cg * 2;   // float4 index of this lane's 8 channels
    const float4 m0 = m4[vbase];
    const float4 m1 = m4[vbase + 1];

    float sc[25];

#pragma unroll
    for (int i = 0; i < 5; ++i) {
        const int hh  = h + i - 2;
        const bool hok = ((unsigned)hh < 256u);
#pragma unroll
        for (int j = 0; j < 5; ++j) {
            const int k  = i * 5 + j;
            const int ww = w + j - 2;
            const bool ok = hok && ((unsigned)ww < 256u);
            float s = 0.0f;
            if (ok) {
                const int np = p + (i - 2) * 256 + (j - 2);  // stays inside batch when ok
                const int a  = np * 8 + cg * 2;
                const float4 r0 = r4[a];
                const float4 r1 = r4[a + 1];
                s = m0.x * r0.x + m0.y * r0.y + m0.z * r0.z + m0.w * r0.w
                  + m1.x * r1.x + m1.y * r1.y + m1.z * r1.z + m1.w * r1.w;
            }
            // reduce the 4 channel-group partial sums (quad-local; DPP, no LDS)
            s += __shfl_xor(s, 1, 64);
            s += __shfl_xor(s, 2, 64);
            sc[k] = s;
        }
    }

    // softmax over the 25 scores (replicated in the 4 lanes of each pixel)
    float mx = sc[0];
#pragma unroll
    for (int k = 1; k < 25; ++k) mx = fmaxf(mx, sc[k]);
    float sum = 0.0f;
#pragma unroll
    for (int k = 0; k < 25; ++k) {
        const float e = __expf(sc[k] - mx);
        sc[k] = e;
        sum  += e;
    }
    const float inv = 1.0f / sum;

    float4 a0 = make_float4(0.f, 0.f, 0.f, 0.f);
    float4 a1 = make_float4(0.f, 0.f, 0.f, 0.f);

#pragma unroll
    for (int i = 0; i < 5; ++i) {
        const int hh  = h + i - 2;
        const bool hok = ((unsigned)hh < 256u);
#pragma unroll
        for (int j = 0; j < 5; ++j) {
            const int k  = i * 5 + j;
            const int ww = w + j - 2;
            const bool ok = hok && ((unsigned)ww < 256u);
            if (ok) {
                const int np = p + (i - 2) * 256 + (j - 2);
                const int a  = np * 8 + cg * 2;
                const float4 v0 = v4[a];
                const float4 v1 = v4[a + 1];
                const float wk = sc[k] * inv;
                a0.x += wk * v0.x; a0.y += wk * v0.y; a0.z += wk * v0.z; a0.w += wk * v0.w;
                a1.x += wk * v1.x; a1.y += wk * v1.y; a1.z += wk * v1.z; a1.w += wk * v1.w;
            }
        }
    }

    o4[vbase]     = a0;
    o4[vbase + 1] = a1;
}

extern "C" void kernel_launch(void* const* d_in, const int* in_sizes, int n_in,
                              void* d_out, int out_size, void* d_ws, size_t ws_size,
                              hipStream_t stream)
{
    const float* main_p = (const float*)d_in[0];
    const float* ref_p  = (const float*)d_in[1];
    const float* rv_p   = (const float*)d_in[2];
    float*       out_p  = (float*)d_out;

    const int npix = in_sizes[0] / 32;        // B*H*W = 131072
    const int blocks = npix / 64;             // 64 pixels per 256-thread block
    local_attn_kernel<<<blocks, 256, 0, stream>>>(main_p, ref_p, rv_p, out_p);
}